// Round 6
// baseline (257.758 us; speedup 1.0000x reference)
//
#include <hip/hip_runtime.h>

// Problem constants (match reference)
constexpr int B_IMG = 8;
constexpr int A_ANCH = 150000;
constexpr int C_CLS = 10;
constexpr int TPB = 256;
constexpr int BA = TPB * 2;                      // 512 anchors per block (APT=2, R3's best)
constexpr int NBX = (A_ANCH + BA - 1) / BA;      // 293
constexpr int NBLK = NBX * B_IMG;                // 2344
constexpr int WPB = TPB / 64;                    // 4 waves per block
constexpr int SEG = NBX * WPB;                   // 1172 wave-partials per image
// ws layout: float att_part[B][SEG], rl_part[B][SEG], np_part[B][SEG], unsigned counter

__global__ __launch_bounds__(TPB) void focal_fused(
    const float* __restrict__ attr,   // (B, A, C)
    const float* __restrict__ regr,   // (B, A, 4)
    const float* __restrict__ anch,   // (A, 4)
    const float* __restrict__ ann,    // (B, 14)
    float* __restrict__ att_part,
    float* __restrict__ rl_part,
    float* __restrict__ np_part,
    unsigned* __restrict__ counter,
    float* __restrict__ out)
{
    // Consecutive blockIdx.x -> consecutive XCDs (round-robin dispatch), so
    // b = blockIdx.x % 8 pins image b to XCD b: anchors (2.4 MB) + that image's
    // attr slab stay L2-resident across graph replays.
    const int b  = blockIdx.x % B_IMG;
    const int bx = blockIdx.x / B_IMG;

    const int a0 = bx * BA + threadIdx.x * 2;
    const bool valid = (a0 < A_ANCH);   // a0 even -> a0+1 valid too

    // ---- issue all global loads upfront (7 independent float4s) ----
    float4 at4[5];
    float4 anA = make_float4(0.f, 0.f, 0.f, 0.f), anB = anA;
    if (valid) {
        const float4* ap = reinterpret_cast<const float4*>(attr + ((size_t)b * A_ANCH + a0) * C_CLS);
#pragma unroll
        for (int j = 0; j < 5; ++j) at4[j] = ap[j];
        const float4* anp = reinterpret_cast<const float4*>(anch) + a0;
        anA = anp[0];
        anB = anp[1];
    }

    // annotation: wave-uniform scalar loads
    const float* annb = ann + b * 14;
    const float bx0 = annb[0], by0 = annb[1], bx1 = annb[2], by1 = annb[3];
    float lab[C_CLS];
#pragma unroll
    for (int c = 0; c < C_CLS; ++c) lab[c] = annb[4 + c];

    const float gw_raw = bx1 - bx0;
    const float gh_raw = by1 - by0;
    const float area = gw_raw * gh_raw;
    const float gcx = bx0 + 0.5f * gw_raw;
    const float gcy = by0 + 0.5f * gh_raw;
    const float gw = fmaxf(gw_raw, 1.0f);
    const float gh = fmaxf(gh_raw, 1.0f);

    const float TH  = (float)(1.0 / 9.0);
    const float SUB = (float)(0.5 / 9.0);
    const float PHI = (float)(1.0 - 0.0001);

    float att_sum = 0.0f;
    float rl_sum = 0.0f;
    float npf = 0.0f;

    if (valid) {
        float av[2 * C_CLS];
#pragma unroll
        for (int j = 0; j < 5; ++j) {
            av[4 * j + 0] = at4[j].x;
            av[4 * j + 1] = at4[j].y;
            av[4 * j + 2] = at4[j].z;
            av[4 * j + 3] = at4[j].w;
        }
        const float4 an[2] = {anA, anB};
#pragma unroll
        for (int k = 0; k < 2; ++k) {
            const float ax0 = an[k].x, ay0 = an[k].y, ax1 = an[k].z, ay1 = an[k].w;
            const float aw = ax1 - ax0;
            const float ah = ay1 - ay0;
            float iw = fminf(ax1, bx1) - fmaxf(ax0, bx0);
            float ih = fminf(ay1, by1) - fmaxf(ay0, by0);
            iw = fmaxf(iw, 0.0f);
            ih = fmaxf(ih, 0.0f);
            const float inter = iw * ih;
            const float uni = fmaxf(aw * ah + area - inter, 1e-8f);
            const float iou = inter / uni;
            const bool pos = (iou >= 0.5f);
            const bool neg = (iou < 0.4f);

            if (pos || neg) {
#pragma unroll
                for (int c = 0; c < C_CLS; ++c) {
                    float p = av[k * C_CLS + c];
                    p = fminf(fmaxf(p, 1e-4f), PHI);
                    const float tgt = pos ? lab[c] : 0.0f;
                    float loss;
                    if (tgt == 1.0f) {
                        const float q = 1.0f - p;
                        loss = 0.25f * (q * q) * (-logf(p));
                    } else {
                        loss = 0.75f * (p * p) * (-logf(1.0f - p));
                    }
                    att_sum += loss;
                }
            }
            if (pos) {
                npf += 1.0f;
                const float acx = ax0 + 0.5f * aw;
                const float acy = ay0 + 0.5f * ah;
                const float t0 = ((gcx - acx) / aw) / 0.1f;
                const float t1 = ((gcy - acy) / ah) / 0.1f;
                const float t2 = logf(gw / aw) / 0.2f;
                const float t3 = logf(gh / ah) / 0.2f;
                const float4 r = *reinterpret_cast<const float4*>(regr + ((size_t)b * A_ANCH + a0 + k) * 4);
                float d;
                d = fabsf(t0 - r.x); rl_sum += (d <= TH) ? 4.5f * d * d : d - SUB;
                d = fabsf(t1 - r.y); rl_sum += (d <= TH) ? 4.5f * d * d : d - SUB;
                d = fabsf(t2 - r.z); rl_sum += (d <= TH) ? 4.5f * d * d : d - SUB;
                d = fabsf(t3 - r.w); rl_sum += (d <= TH) ? 4.5f * d * d : d - SUB;
            }
        }
    }

    // wave (64-lane) reduce; lane 0 stores this wave's partial directly.
#pragma unroll
    for (int off = 32; off > 0; off >>= 1) {
        att_sum += __shfl_down(att_sum, off);
        rl_sum  += __shfl_down(rl_sum, off);
        npf     += __shfl_down(npf, off);
    }
    const int wave = threadIdx.x >> 6;
    const int lane = threadIdx.x & 63;
    if (lane == 0) {
        const int idx = b * SEG + bx * WPB + wave;
        att_part[idx] = att_sum;
        rl_part[idx]  = rl_sum;
        np_part[idx]  = npf;
    }

    // ---- last-block ticket: the final arriving block reduces everything ----
    __shared__ int s_last;
    __threadfence();                      // make partial stores device-visible
    if (threadIdx.x == 0) {
        const unsigned old = atomicAdd(counter, 1u);
        s_last = (old == (unsigned)(NBLK - 1)) ? 1 : 0;
    }
    __syncthreads();
    if (s_last == 0) return;

    __threadfence();                      // acquire: see all blocks' partials
    __shared__ float s_am[B_IMG], s_rm[B_IMG];
#pragma unroll
    for (int rep = 0; rep < 2; ++rep) {
        const int img = wave + rep * WPB;         // 4 waves x 2 = 8 images
        float as = 0.0f, rs = 0.0f, ns = 0.0f;
        const float* ap  = att_part + img * SEG;
        const float* rp  = rl_part + img * SEG;
        const float* npp = np_part + img * SEG;
        for (int i = lane; i < SEG; i += 64) {
            as += ap[i];
            rs += rp[i];
            ns += npp[i];
        }
#pragma unroll
        for (int off = 32; off > 0; off >>= 1) {
            as += __shfl_down(as, off);
            rs += __shfl_down(rs, off);
            ns += __shfl_down(ns, off);
        }
        if (lane == 0) {
            const double npd = (double)ns;
            const double den = npd > 0.0 ? npd : 1.0;
            s_am[img] = (float)((double)as / den);
            s_rm[img] = (npd > 0.0) ? (float)((double)rs / (den * 4.0)) : 0.0f;
        }
    }
    __syncthreads();
    if (threadIdx.x == 0) {
        double am = 0.0, rm = 0.0;
#pragma unroll
        for (int i = 0; i < B_IMG; ++i) { am += (double)s_am[i]; rm += (double)s_rm[i]; }
        out[0] = (float)(am / (double)B_IMG);
        out[1] = (float)(rm / (double)B_IMG);
    }
}

extern "C" void kernel_launch(void* const* d_in, const int* in_sizes, int n_in,
                              void* d_out, int out_size, void* d_ws, size_t ws_size,
                              hipStream_t stream) {
    const float* attr = (const float*)d_in[0];   // attributes (B,A,C)
    const float* regr = (const float*)d_in[1];   // regressions (B,A,4)
    const float* anch = (const float*)d_in[2];   // anchors (1,A,4)
    const float* ann  = (const float*)d_in[3];   // annotations (B,14)
    float* out = (float*)d_out;

    float* att_part = (float*)d_ws;
    float* rl_part  = att_part + B_IMG * SEG;
    float* np_part  = rl_part + B_IMG * SEG;
    unsigned* counter = (unsigned*)(np_part + B_IMG * SEG);

    // Zero only the ticket counter each launch (partials are fully overwritten).
    hipMemsetAsync(counter, 0, sizeof(unsigned), stream);

    focal_fused<<<NBLK, TPB, 0, stream>>>(attr, regr, anch, ann,
                                          att_part, rl_part, np_part, counter, out);
}

// Round 7
// 47.826 us; speedup vs baseline: 5.3895x; 5.3895x over previous
//
#include <hip/hip_runtime.h>

// Problem constants (match reference)
constexpr int B_IMG = 8;
constexpr int A_ANCH = 150000;
constexpr int C_CLS = 10;
constexpr int TPB = 256;
constexpr int BA = TPB * 2;                      // 512 anchors per block (APT=2)
constexpr int NBX = (A_ANCH + BA - 1) / BA;      // 293
constexpr int NBLK = NBX * B_IMG;                // 2344
constexpr int REP = 4;                           // accumulator replicas per image
constexpr double SCALE = 1048576.0;              // 2^20 fixed-point

// One accumulator slot per 64B line: no cross-slot line contention.
struct alignas(64) AccSlot {
    unsigned long long att, rl, np;
    unsigned long long pad[5];
};

__global__ __launch_bounds__(TPB) void focal_fused(
    const float* __restrict__ attr,   // (B, A, C)
    const float* __restrict__ regr,   // (B, A, 4)
    const float* __restrict__ anch,   // (A, 4)
    const float* __restrict__ ann,    // (B, 14)
    AccSlot* __restrict__ acc,        // [B_IMG * REP]
    unsigned* __restrict__ counter,
    float* __restrict__ out)
{
    // b = bid % 8: with round-robin XCD dispatch, image b's blocks share an XCD
    // -> the 2.4MB anchor array stays L2-resident per XCD across that image.
    const int b  = blockIdx.x % B_IMG;
    const int bx = blockIdx.x / B_IMG;

    const int a0 = bx * BA + threadIdx.x * 2;
    const bool valid = (a0 < A_ANCH);   // a0 even -> a0+1 valid too

    // ---- issue all global loads upfront (7 independent float4s) ----
    float4 at4[5];
    float4 anA = make_float4(0.f, 0.f, 0.f, 0.f), anB = anA;
    if (valid) {
        const float4* ap = reinterpret_cast<const float4*>(attr + ((size_t)b * A_ANCH + a0) * C_CLS);
#pragma unroll
        for (int j = 0; j < 5; ++j) at4[j] = ap[j];
        const float4* anp = reinterpret_cast<const float4*>(anch) + a0;
        anA = anp[0];
        anB = anp[1];
    }

    // annotation: wave-uniform scalar loads
    const float* annb = ann + b * 14;
    const float bx0 = annb[0], by0 = annb[1], bx1 = annb[2], by1 = annb[3];
    float lab[C_CLS];
#pragma unroll
    for (int c = 0; c < C_CLS; ++c) lab[c] = annb[4 + c];

    const float gw_raw = bx1 - bx0;
    const float gh_raw = by1 - by0;
    const float area = gw_raw * gh_raw;
    const float gcx = bx0 + 0.5f * gw_raw;
    const float gcy = by0 + 0.5f * gh_raw;
    const float gw = fmaxf(gw_raw, 1.0f);
    const float gh = fmaxf(gh_raw, 1.0f);

    const float TH  = (float)(1.0 / 9.0);
    const float SUB = (float)(0.5 / 9.0);
    const float PHI = (float)(1.0 - 0.0001);

    float att_sum = 0.0f;
    float rl_sum = 0.0f;
    float npf = 0.0f;

    if (valid) {
        float av[2 * C_CLS];
#pragma unroll
        for (int j = 0; j < 5; ++j) {
            av[4 * j + 0] = at4[j].x;
            av[4 * j + 1] = at4[j].y;
            av[4 * j + 2] = at4[j].z;
            av[4 * j + 3] = at4[j].w;
        }
        const float4 an[2] = {anA, anB};
#pragma unroll
        for (int k = 0; k < 2; ++k) {
            const float ax0 = an[k].x, ay0 = an[k].y, ax1 = an[k].z, ay1 = an[k].w;
            const float aw = ax1 - ax0;
            const float ah = ay1 - ay0;
            float iw = fminf(ax1, bx1) - fmaxf(ax0, bx0);
            float ih = fminf(ay1, by1) - fmaxf(ay0, by0);
            iw = fmaxf(iw, 0.0f);
            ih = fmaxf(ih, 0.0f);
            const float inter = iw * ih;
            const float uni = fmaxf(aw * ah + area - inter, 1e-8f);
            const float iou = inter / uni;
            const bool pos = (iou >= 0.5f);
            const bool neg = (iou < 0.4f);

            if (pos || neg) {
#pragma unroll
                for (int c = 0; c < C_CLS; ++c) {
                    float p = av[k * C_CLS + c];
                    p = fminf(fmaxf(p, 1e-4f), PHI);
                    const float tgt = pos ? lab[c] : 0.0f;
                    float loss;
                    if (tgt == 1.0f) {
                        const float q = 1.0f - p;
                        loss = 0.25f * (q * q) * (-logf(p));
                    } else {
                        loss = 0.75f * (p * p) * (-logf(1.0f - p));
                    }
                    att_sum += loss;
                }
            }
            if (pos) {
                npf += 1.0f;
                const float acx = ax0 + 0.5f * aw;
                const float acy = ay0 + 0.5f * ah;
                const float t0 = ((gcx - acx) / aw) / 0.1f;
                const float t1 = ((gcy - acy) / ah) / 0.1f;
                const float t2 = logf(gw / aw) / 0.2f;
                const float t3 = logf(gh / ah) / 0.2f;
                const float4 r = *reinterpret_cast<const float4*>(regr + ((size_t)b * A_ANCH + a0 + k) * 4);
                float d;
                d = fabsf(t0 - r.x); rl_sum += (d <= TH) ? 4.5f * d * d : d - SUB;
                d = fabsf(t1 - r.y); rl_sum += (d <= TH) ? 4.5f * d * d : d - SUB;
                d = fabsf(t2 - r.z); rl_sum += (d <= TH) ? 4.5f * d * d : d - SUB;
                d = fabsf(t3 - r.w); rl_sum += (d <= TH) ? 4.5f * d * d : d - SUB;
            }
        }
    }

    // wave (64-lane) reduce
#pragma unroll
    for (int off = 32; off > 0; off >>= 1) {
        att_sum += __shfl_down(att_sum, off);
        rl_sum  += __shfl_down(rl_sum, off);
        npf     += __shfl_down(npf, off);
    }
    __shared__ float s_att[TPB / 64];
    __shared__ float s_rl[TPB / 64];
    __shared__ float s_np[TPB / 64];
    const int wave = threadIdx.x >> 6;
    const int lane = threadIdx.x & 63;
    if (lane == 0) { s_att[wave] = att_sum; s_rl[wave] = rl_sum; s_np[wave] = npf; }
    __syncthreads();

    // ---- fixed-point device atomics (coherent point, NO fences) + ticket ----
    __shared__ int s_last;
    if (threadIdx.x == 0) {
        float a0s = 0.0f, r0 = 0.0f, n0 = 0.0f;
#pragma unroll
        for (int w = 0; w < TPB / 64; ++w) { a0s += s_att[w]; r0 += s_rl[w]; n0 += s_np[w]; }
        AccSlot* slot = &acc[b * REP + (bx & (REP - 1))];
        const unsigned long long av = (unsigned long long)(long long)llrint((double)a0s * SCALE);
        const unsigned long long rv = (unsigned long long)(long long)llrint((double)r0 * SCALE);
        const unsigned long long nv = (unsigned long long)llrintf(n0);
        if (av) atomicAdd(&slot->att, av);
        if (rv) atomicAdd(&slot->rl, rv);
        if (nv) atomicAdd(&slot->np, nv);
        // Drain value-atomics to the coherent point before taking the ticket.
        asm volatile("s_waitcnt vmcnt(0)" ::: "memory");
        const unsigned old = atomicAdd(counter, 1u);
        s_last = (old == (unsigned)(NBLK - 1)) ? 1 : 0;
    }
    __syncthreads();
    if (s_last == 0) return;

    // ---- last block: read slots via atomic RMW (always-fresh), finalize ----
    __shared__ unsigned long long g_att[B_IMG * REP], g_rl[B_IMG * REP], g_np[B_IMG * REP];
    if (threadIdx.x < B_IMG * REP) {
        AccSlot* slot = &acc[threadIdx.x];
        g_att[threadIdx.x] = atomicAdd(&slot->att, 0ull);
        g_rl[threadIdx.x]  = atomicAdd(&slot->rl, 0ull);
        g_np[threadIdx.x]  = atomicAdd(&slot->np, 0ull);
    }
    __syncthreads();
    if (threadIdx.x == 0) {
        double am = 0.0, rm = 0.0;
#pragma unroll
        for (int img = 0; img < B_IMG; ++img) {
            unsigned long long ia = 0, ir = 0, in = 0;
#pragma unroll
            for (int r = 0; r < REP; ++r) {
                ia += g_att[img * REP + r];
                ir += g_rl[img * REP + r];
                in += g_np[img * REP + r];
            }
            const double as = (double)ia / SCALE;
            const double rs = (double)ir / SCALE;
            const double npd = (double)in;
            const double den = npd > 0.0 ? npd : 1.0;
            am += as / den;
            if (in > 0) rm += rs / (den * 4.0);
        }
        out[0] = (float)(am / (double)B_IMG);
        out[1] = (float)(rm / (double)B_IMG);
    }
}

extern "C" void kernel_launch(void* const* d_in, const int* in_sizes, int n_in,
                              void* d_out, int out_size, void* d_ws, size_t ws_size,
                              hipStream_t stream) {
    const float* attr = (const float*)d_in[0];   // attributes (B,A,C)
    const float* regr = (const float*)d_in[1];   // regressions (B,A,4)
    const float* anch = (const float*)d_in[2];   // anchors (1,A,4)
    const float* ann  = (const float*)d_in[3];   // annotations (B,14)
    float* out = (float*)d_out;

    AccSlot* acc = (AccSlot*)d_ws;
    unsigned* counter = (unsigned*)(acc + B_IMG * REP);

    // Zero accumulators + ticket each launch (harness doesn't re-poison ws).
    hipMemsetAsync(d_ws, 0, B_IMG * REP * sizeof(AccSlot) + sizeof(unsigned), stream);

    focal_fused<<<NBLK, TPB, 0, stream>>>(attr, regr, anch, ann, acc, counter, out);
}

// Round 8
// 23.269 us; speedup vs baseline: 11.0772x; 2.0553x over previous
//
#include <hip/hip_runtime.h>

// Problem constants (match reference)
constexpr int B_IMG = 8;
constexpr int A_ANCH = 150000;
constexpr int C_CLS = 10;
constexpr int TPB = 256;
// grid.x blocks over anchors (2 anchors/thread), grid.y = image
constexpr int NBX = (A_ANCH + TPB * 2 - 1) / (TPB * 2);   // 293

// ws layout: float att_part[B][NBX], float rl_part[B][NBX], float np_part[B][NBX]
// No atomics: every block stores its partials unconditionally; finalize reduces.
__global__ __launch_bounds__(TPB) void focal_main(
    const float* __restrict__ attr,   // (B, A, C)
    const float* __restrict__ regr,   // (B, A, 4)
    const float* __restrict__ anch,   // (A, 4)
    const float* __restrict__ ann,    // (B, 14)
    float* __restrict__ att_part,
    float* __restrict__ rl_part,
    float* __restrict__ np_part)
{
    const int b = blockIdx.y;
    const int a0 = (blockIdx.x * TPB + threadIdx.x) * 2;
    const bool valid = (a0 < A_ANCH);   // A even, so a0 valid => a0+1 valid

    // ---- issue ALL global loads for this thread upfront (7 independent float4s) ----
    float4 at4[5];   // 2 anchors x 10 classes
    float4 an4[2];   // 2 anchor boxes
    if (valid) {
        const float4* ap = reinterpret_cast<const float4*>(attr + ((size_t)b * A_ANCH + a0) * C_CLS);
#pragma unroll
        for (int j = 0; j < 5; ++j) at4[j] = ap[j];
        const float4* anp = reinterpret_cast<const float4*>(anch) + a0;
        an4[0] = anp[0];
        an4[1] = anp[1];
    }

    // annotation is wave-uniform -> scalar loads
    const float* annb = ann + b * 14;
    const float bx0 = annb[0], by0 = annb[1], bx1 = annb[2], by1 = annb[3];
    float lab[C_CLS];
#pragma unroll
    for (int c = 0; c < C_CLS; ++c) lab[c] = annb[4 + c];

    const float gw_raw = bx1 - bx0;
    const float gh_raw = by1 - by0;
    const float area = gw_raw * gh_raw;
    const float gcx = bx0 + 0.5f * gw_raw;
    const float gcy = by0 + 0.5f * gh_raw;
    const float gw = fmaxf(gw_raw, 1.0f);
    const float gh = fmaxf(gh_raw, 1.0f);

    const float TH  = (float)(1.0 / 9.0);
    const float SUB = (float)(0.5 / 9.0);
    const float PHI = (float)(1.0 - 0.0001);

    float att_sum = 0.0f;
    float rl_sum = 0.0f;
    float npf = 0.0f;

    if (valid) {
        float av[20];
#pragma unroll
        for (int j = 0; j < 5; ++j) {
            av[4 * j + 0] = at4[j].x;
            av[4 * j + 1] = at4[j].y;
            av[4 * j + 2] = at4[j].z;
            av[4 * j + 3] = at4[j].w;
        }

#pragma unroll
        for (int k = 0; k < 2; ++k) {
            const float ax0 = an4[k].x, ay0 = an4[k].y, ax1 = an4[k].z, ay1 = an4[k].w;
            const float aw = ax1 - ax0;
            const float ah = ay1 - ay0;
            float iw = fminf(ax1, bx1) - fmaxf(ax0, bx0);
            float ih = fminf(ay1, by1) - fmaxf(ay0, by0);
            iw = fmaxf(iw, 0.0f);
            ih = fmaxf(ih, 0.0f);
            const float inter = iw * ih;
            const float uni = fmaxf(aw * ah + area - inter, 1e-8f);
            const float iou = inter / uni;
            const bool pos = (iou >= 0.5f);
            const bool neg = (iou < 0.4f);

            if (pos || neg) {
#pragma unroll
                for (int c = 0; c < C_CLS; ++c) {
                    float p = av[k * C_CLS + c];
                    p = fminf(fmaxf(p, 1e-4f), PHI);
                    const float tgt = pos ? lab[c] : 0.0f;
                    float loss;
                    if (tgt == 1.0f) {
                        const float q = 1.0f - p;
                        loss = 0.25f * (q * q) * (-__logf(p));          // native v_log_f32
                    } else {
                        loss = 0.75f * (p * p) * (-__logf(1.0f - p));   // native v_log_f32
                    }
                    att_sum += loss;
                }
            }
            if (pos) {
                npf += 1.0f;
                const float acx = ax0 + 0.5f * aw;
                const float acy = ay0 + 0.5f * ah;
                const float t0 = ((gcx - acx) / aw) / 0.1f;
                const float t1 = ((gcy - acy) / ah) / 0.1f;
                const float t2 = __logf(gw / aw) / 0.2f;
                const float t3 = __logf(gh / ah) / 0.2f;
                const float4 r = *reinterpret_cast<const float4*>(regr + ((size_t)b * A_ANCH + a0 + k) * 4);
                float d;
                d = fabsf(t0 - r.x); rl_sum += (d <= TH) ? 4.5f * d * d : d - SUB;
                d = fabsf(t1 - r.y); rl_sum += (d <= TH) ? 4.5f * d * d : d - SUB;
                d = fabsf(t2 - r.z); rl_sum += (d <= TH) ? 4.5f * d * d : d - SUB;
                d = fabsf(t3 - r.w); rl_sum += (d <= TH) ? 4.5f * d * d : d - SUB;
            }
        }
    }

    // wave (64-lane) reduce
#pragma unroll
    for (int off = 32; off > 0; off >>= 1) {
        att_sum += __shfl_down(att_sum, off);
        rl_sum  += __shfl_down(rl_sum, off);
        npf     += __shfl_down(npf, off);
    }

    __shared__ float s_att[TPB / 64];
    __shared__ float s_rl[TPB / 64];
    __shared__ float s_np[TPB / 64];
    const int wave = threadIdx.x >> 6;
    const int lane = threadIdx.x & 63;
    if (lane == 0) { s_att[wave] = att_sum; s_rl[wave] = rl_sum; s_np[wave] = npf; }
    __syncthreads();
    if (threadIdx.x == 0) {
        float a0s = 0.0f, r0 = 0.0f, n0 = 0.0f;
#pragma unroll
        for (int w = 0; w < TPB / 64; ++w) { a0s += s_att[w]; r0 += s_rl[w]; n0 += s_np[w]; }
        const int idx = b * NBX + blockIdx.x;
        att_part[idx] = a0s;            // plain stores, no atomics
        rl_part[idx]  = r0;
        np_part[idx]  = n0;             // counts < 2^24, exact in float
    }
}

// One block, 8 waves: wave b tree-reduces image b's NBX partials.
__global__ __launch_bounds__(512) void focal_finalize(
    const float* __restrict__ att_part,
    const float* __restrict__ rl_part,
    const float* __restrict__ np_part,
    float* __restrict__ out)
{
    const int wave = threadIdx.x >> 6;
    const int lane = threadIdx.x & 63;
    float as = 0.0f, rs = 0.0f, ns = 0.0f;
    if (wave < B_IMG) {
        for (int i = lane; i < NBX; i += 64) {
            as += att_part[wave * NBX + i];
            rs += rl_part[wave * NBX + i];
            ns += np_part[wave * NBX + i];
        }
    }
#pragma unroll
    for (int off = 32; off > 0; off >>= 1) {
        as += __shfl_down(as, off);
        rs += __shfl_down(rs, off);
        ns += __shfl_down(ns, off);
    }
    __shared__ float sa[B_IMG], sr[B_IMG], sn[B_IMG];
    if (lane == 0 && wave < B_IMG) { sa[wave] = as; sr[wave] = rs; sn[wave] = ns; }
    __syncthreads();
    if (threadIdx.x == 0) {
        double am = 0.0, rm = 0.0;
        for (int b = 0; b < B_IMG; ++b) {
            const double npd = (double)sn[b];
            const double npf = npd > 0.0 ? npd : 1.0;
            am += (double)sa[b] / npf;
            if (npd > 0.0) rm += (double)sr[b] / (npf * 4.0);
        }
        out[0] = (float)(am / (double)B_IMG);
        out[1] = (float)(rm / (double)B_IMG);
    }
}

extern "C" void kernel_launch(void* const* d_in, const int* in_sizes, int n_in,
                              void* d_out, int out_size, void* d_ws, size_t ws_size,
                              hipStream_t stream) {
    const float* attr = (const float*)d_in[0];   // attributes (B,A,C)
    const float* regr = (const float*)d_in[1];   // regressions (B,A,4)
    const float* anch = (const float*)d_in[2];   // anchors (1,A,4)
    const float* ann  = (const float*)d_in[3];   // annotations (B,14)
    float* out = (float*)d_out;

    float* att_part = (float*)d_ws;
    float* rl_part  = att_part + B_IMG * NBX;
    float* np_part  = rl_part + B_IMG * NBX;
    // All partials are stored unconditionally every launch -> no memset needed.

    dim3 grid(NBX, B_IMG);
    focal_main<<<grid, TPB, 0, stream>>>(attr, regr, anch, ann, att_part, rl_part, np_part);
    focal_finalize<<<1, 512, 0, stream>>>(att_part, rl_part, np_part, out);
}